// Round 12
// baseline (244.646 us; speedup 1.0000x reference)
//
#include <hip/hip_runtime.h>
#include <hip/hip_bf16.h>
#include <cmath>

#define NN   20000              // nodes
#define NE   320000             // raw edges
#define EE   (NE + NN)          // edges incl. self-loops
#define NG   64                 // graphs
#define NH   4                  // heads
#define NC   64                 // channels/head
#define HIDD 256                // NH*NC
#define IND  128                // input feature dim
#define LATD 64                 // latent dim
#define NEGS 0.2f
#define BNEPS 1e-5f
#define MPAD 20096              // 157 * 128 (GEMM M padding)
#define PSPLIT 16               // pooling chunks per graph
#define NB   ((NN + 255) / 256) // scan blocks (79)

// GEMM tile
#define BM 128
#define BN 64
#define BK 64

typedef __attribute__((ext_vector_type(8))) short short8;
typedef __attribute__((ext_vector_type(4))) float f32x4;

__device__ inline int lower_bound_i(const int* __restrict__ b, int n, int key) {
    int lo = 0, hi = n;
    while (lo < hi) { int mid = (lo + hi) >> 1; if (b[mid] < key) lo = mid + 1; else hi = mid; }
    return lo;
}

__device__ inline float sel4(float4 v, int h) {
    float r = v.x;
    r = (h == 1) ? v.y : r;
    r = (h == 2) ? v.z : r;
    r = (h == 3) ? v.w : r;
    return r;
}

__device__ inline float bf2f(unsigned short u) {
    return __uint_as_float(((unsigned int)u) << 16);
}

__global__ void k_zero(int* __restrict__ p, int n) {
    int i = blockIdx.x * blockDim.x + threadIdx.x;
    if (i < n) p[i] = 0;
}

// ---------- fp32 -> bf16 cast of x ----------
__global__ void k_cast_x(const float* __restrict__ x, __hip_bfloat16* __restrict__ hbx) {
    int i = blockIdx.x * blockDim.x + threadIdx.x;     // over NN*IND/4
    if (i >= NN * IND / 4) return;
    float4 v = ((const float4*)x)[i];
    union { __hip_bfloat16 b[4]; ushort4 u; } cv;
    cv.b[0] = __float2bfloat16(v.x); cv.b[1] = __float2bfloat16(v.y);
    cv.b[2] = __float2bfloat16(v.z); cv.b[3] = __float2bfloat16(v.w);
    ((ushort4*)hbx)[i] = cv.u;
}

// ---------- all 3 layers: W[K][256] -> Wt[256][K] bf16, one dispatch ----------
__global__ void k_cast_wt_all(const float* __restrict__ W0, const float* __restrict__ Wr,
                              __hip_bfloat16* __restrict__ Wt3) {
    int k = blockIdx.x;          // 0..255
    int l = blockIdx.y;          // layer
    int n = threadIdx.x;         // 256
    int K = (l == 0) ? IND : HIDD;
    if (k >= K) return;
    const float* W = (l == 0) ? W0 : (Wr + (size_t)(l - 1) * HIDD * HIDD);
    size_t off = (l == 0) ? 0 : ((size_t)HIDD * IND + (size_t)(l - 1) * HIDD * HIDD);
    Wt3[off + (size_t)n * K + k] = __float2bfloat16(W[(size_t)k * HIDD + n]);
}

// ---------- CSR build ----------
__global__ void k_hist(const int* __restrict__ ei, int* __restrict__ deg) {
    int e = blockIdx.x * blockDim.x + threadIdx.x;
    if (e >= EE) return;
    int d = (e < NE) ? ei[NE + e] : (e - NE);
    atomicAdd(&deg[d], 1);
}

__global__ __launch_bounds__(256) void k_blocksum(const int* __restrict__ deg,
                                                  int* __restrict__ bsum) {
    __shared__ int s[256];
    int i = blockIdx.x * 256 + threadIdx.x;
    s[threadIdx.x] = (i < NN) ? deg[i] : 0;
    __syncthreads();
    for (int off = 128; off > 0; off >>= 1) {
        if (threadIdx.x < off) s[threadIdx.x] += s[threadIdx.x + off];
        __syncthreads();
    }
    if (threadIdx.x == 0) bsum[blockIdx.x] = s[0];
}

__global__ __launch_bounds__(128) void k_scanbs(const int* __restrict__ bsum,
                                                int* __restrict__ boff,
                                                int* __restrict__ row_ptr) {
    __shared__ int s[128];
    int tid = threadIdx.x;
    int v = (tid < NB) ? bsum[tid] : 0;
    s[tid] = v;
    __syncthreads();
    for (int off = 1; off < 128; off <<= 1) {
        int t = (tid >= off) ? s[tid - off] : 0;
        __syncthreads();
        s[tid] += t;
        __syncthreads();
    }
    if (tid < NB) boff[tid] = s[tid] - v;          // exclusive block offset
    if (tid == NB - 1) row_ptr[NN] = s[tid];       // total (= EE)
}

__global__ __launch_bounds__(256) void k_scanapply(const int* __restrict__ deg,
                                                   const int* __restrict__ boff,
                                                   int* __restrict__ row_ptr,
                                                   int* __restrict__ cursor) {
    __shared__ int s[256];
    int i = blockIdx.x * 256 + threadIdx.x;
    int v = (i < NN) ? deg[i] : 0;
    s[threadIdx.x] = v;
    __syncthreads();
    for (int off = 1; off < 256; off <<= 1) {
        int t = (threadIdx.x >= off) ? s[threadIdx.x - off] : 0;
        __syncthreads();
        s[threadIdx.x] += t;
        __syncthreads();
    }
    if (i < NN) {
        int excl = boff[blockIdx.x] + s[threadIdx.x] - v;
        row_ptr[i] = excl; cursor[i] = excl;
    }
}

__global__ void k_csr_scatter(const int* __restrict__ ei, int* __restrict__ cursor,
                              int* __restrict__ col_idx) {
    int e = blockIdx.x * blockDim.x + threadIdx.x;
    if (e >= EE) return;
    int s, d;
    if (e < NE) { s = ei[e]; d = ei[NE + e]; } else { s = d = e - NE; }
    int pos = atomicAdd(&cursor[d], 1);
    col_idx[pos] = s;
}

// ---------- MFMA GEMM + fused attention scalars ----------
// xpb2 layout: [2 slices][MPAD][128] bf16 (slice = channel-half, 5.15 MB each)
__global__ __launch_bounds__(256) void k_gemm(const short* __restrict__ A,
                                              const short* __restrict__ Bt,
                                              int K, __hip_bfloat16* __restrict__ Cb,
                                              const float* __restrict__ a_src,
                                              const float* __restrict__ a_dst,
                                              float* __restrict__ al_s,
                                              float* __restrict__ al_d) {
    __shared__ char As[BM * BK * 2];   // 16 KB, XOR-swizzled
    __shared__ char Bs[BN * BK * 2];   // 8 KB
    __shared__ float redS[2][BM];      // 1 KB
    __shared__ float redD[2][BM];      // 1 KB
    int tid = threadIdx.x;
    int lane = tid & 63;
    int wid = tid >> 6;
    int wm = wid >> 1, wn = wid & 1;               // 2x2 wave grid
    int bm0 = blockIdx.x * BM, bn0 = blockIdx.y * BN;
    int r16 = lane & 15, kg = lane >> 4;

    f32x4 acc[4][2];
    #pragma unroll
    for (int m = 0; m < 4; ++m)
        #pragma unroll
        for (int n = 0; n < 2; ++n) acc[m][n] = (f32x4){0.f, 0.f, 0.f, 0.f};

    for (int k0 = 0; k0 < K; k0 += BK) {
        __syncthreads();
        #pragma unroll
        for (int p = 0; p < 4; ++p) {
            int row = p * 32 + (tid >> 3);
            int cg  = tid & 7;
            uint4 v = *(const uint4*)(A + (size_t)(bm0 + row) * K + k0 + cg * 8);
            *(uint4*)(As + row * 128 + ((cg * 16) ^ ((row & 7) << 4))) = v;
        }
        #pragma unroll
        for (int p = 0; p < 2; ++p) {
            int row = p * 32 + (tid >> 3);
            int cg  = tid & 7;
            uint4 v = *(const uint4*)(Bt + (size_t)(bn0 + row) * K + k0 + cg * 8);
            *(uint4*)(Bs + row * 128 + ((cg * 16) ^ ((row & 7) << 4))) = v;
        }
        __syncthreads();
        #pragma unroll
        for (int kk = 0; kk < 2; ++kk) {
            short8 af[4], bfr[2];
            int kb = (kk * 32 + kg * 8) * 2;
            #pragma unroll
            for (int m = 0; m < 4; ++m) {
                int row = wm * 64 + m * 16 + r16;
                af[m] = *(const short8*)(As + row * 128 + (kb ^ ((row & 7) << 4)));
            }
            #pragma unroll
            for (int n = 0; n < 2; ++n) {
                int row = wn * 32 + n * 16 + r16;
                bfr[n] = *(const short8*)(Bs + row * 128 + (kb ^ ((row & 7) << 4)));
            }
            #pragma unroll
            for (int m = 0; m < 4; ++m)
                #pragma unroll
                for (int n = 0; n < 2; ++n)
                    acc[m][n] = __builtin_amdgcn_mfma_f32_16x16x32_bf16(af[m], bfr[n], acc[m][n], 0, 0, 0);
        }
    }

    // ---- C store (bf16, channel-half-sliced layout) ----
    #pragma unroll
    for (int m = 0; m < 4; ++m) {
        int row = bm0 + wm * 64 + m * 16 + kg * 4;
        #pragma unroll
        for (int n = 0; n < 2; ++n) {
            int col = bn0 + wn * 32 + n * 16 + r16;
            size_t base = (size_t)(col >> 7) * MPAD * 128 + (col & 127);
            #pragma unroll
            for (int r = 0; r < 4; ++r)
                Cb[base + (size_t)(row + r) * 128] = __float2bfloat16(acc[m][n][r]);
        }
    }

    // ---- fused attention scalars: al_s/al_d[row][head=blockIdx.y] ----
    int headbase = bn0;                              // = blockIdx.y * 64
    float as0 = a_src[headbase + wn * 32 + r16];
    float as1 = a_src[headbase + wn * 32 + 16 + r16];
    float ad0 = a_dst[headbase + wn * 32 + r16];
    float ad1 = a_dst[headbase + wn * 32 + 16 + r16];
    #pragma unroll
    for (int m = 0; m < 4; ++m) {
        #pragma unroll
        for (int r = 0; r < 4; ++r) {
            float ps = as0 * acc[m][0][r] + as1 * acc[m][1][r];
            float pd = ad0 * acc[m][0][r] + ad1 * acc[m][1][r];
            #pragma unroll
            for (int msk = 1; msk < 16; msk <<= 1) {
                ps += __shfl_xor(ps, msk, 64);
                pd += __shfl_xor(pd, msk, 64);
            }
            if (r16 == 0) {
                int rl = wm * 64 + m * 16 + kg * 4 + r;
                redS[wn][rl] = ps;
                redD[wn][rl] = pd;
            }
        }
    }
    __syncthreads();
    if (tid < BM) {
        int node = bm0 + tid;
        al_s[node * NH + blockIdx.y] = redS[0][tid] + redS[1][tid];
        al_d[node * NH + blockIdx.y] = redD[0][tid] + redD[1][tid];
    }
}

// ---------- fused edge-softmax + gather-aggregate + bias/BN/ReLU, channel-half slice ----------
// wave per node, unroll-4; lane covers 2 channels of this slice (ushort2 gathers).
// Per-dispatch gather table = [MPAD][128] bf16 = 5.15 MB (~per-XCD L2).
#define EDGE_BODY(I) \
    { float l = as##I + adh; l = l > 0.f ? l : NEGS * l; \
      float wt = __expf(l); den##I += wt; \
      acc##I.x = fmaf(wt, bf2f((unsigned short)(xv##I & 0xffffu)), acc##I.x); \
      acc##I.y = fmaf(wt, bf2f((unsigned short)(xv##I >> 16)), acc##I.y); }

__global__ __launch_bounds__(256) void k_gat_agg2(
        const int* __restrict__ row_ptr, const int* __restrict__ col_idx,
        const float* __restrict__ al_s, const float* __restrict__ al_d,
        const __hip_bfloat16* __restrict__ xps,      // slice base: [MPAD][128]
        const float* __restrict__ bias, const float* __restrict__ bg,
        const float* __restrict__ bb, const float* __restrict__ bm,
        const float* __restrict__ bv,
        __hip_bfloat16* __restrict__ hb, int slice) {
    int wid = threadIdx.x >> 6, lane = threadIdx.x & 63;
    int node = blockIdx.x * 4 + wid;
    if (node >= NN) return;
    int lo = row_ptr[node], hi = row_ptr[node + 1];
    int gc = slice * 128 + lane * 2;                 // global channel of .x
    int hsel = gc >> 6;                              // head
    float adh = sel4(((const float4*)al_d)[node], hsel);

    float2 acc0 = {0,0}, acc1 = {0,0}, acc2 = {0,0}, acc3 = {0,0};
    float den0 = 0.f, den1 = 0.f, den2 = 0.f, den3 = 0.f;

    int e = lo;
    for (; e + 3 < hi; e += 4) {
        int sc0 = col_idx[e], sc1 = col_idx[e + 1], sc2 = col_idx[e + 2], sc3 = col_idx[e + 3];
        float as0 = al_s[sc0 * NH + hsel];
        float as1 = al_s[sc1 * NH + hsel];
        float as2 = al_s[sc2 * NH + hsel];
        float as3 = al_s[sc3 * NH + hsel];
        unsigned int xv0 = *(const unsigned int*)(xps + (size_t)sc0 * 128 + lane * 2);
        unsigned int xv1 = *(const unsigned int*)(xps + (size_t)sc1 * 128 + lane * 2);
        unsigned int xv2 = *(const unsigned int*)(xps + (size_t)sc2 * 128 + lane * 2);
        unsigned int xv3 = *(const unsigned int*)(xps + (size_t)sc3 * 128 + lane * 2);
        EDGE_BODY(0) EDGE_BODY(1) EDGE_BODY(2) EDGE_BODY(3)
    }
    for (; e < hi; ++e) {
        int sc0 = col_idx[e];
        float as0 = al_s[sc0 * NH + hsel];
        unsigned int xv0 = *(const unsigned int*)(xps + (size_t)sc0 * 128 + lane * 2);
        EDGE_BODY(0)
    }

    float den = (den0 + den1) + (den2 + den3);
    float inv = 1.f / (den + 1e-16f);
    float2 acc;
    acc.x = ((acc0.x + acc1.x) + (acc2.x + acc3.x)) * inv;
    acc.y = ((acc0.y + acc1.y) + (acc2.y + acc3.y)) * inv;

    // epilogue: bias + BN(eval) + ReLU at global channels gc, gc+1
    float2 bi = *(const float2*)(bias + gc);
    float2 gg = *(const float2*)(bg + gc);
    float2 be = *(const float2*)(bb + gc);
    float2 mn = *(const float2*)(bm + gc);
    float2 vr = *(const float2*)(bv + gc);
    float vx = (acc.x + bi.x - mn.x) * rsqrtf(vr.x + BNEPS) * gg.x + be.x;
    float vy = (acc.y + bi.y - mn.y) * rsqrtf(vr.y + BNEPS) * gg.y + be.y;
    vx = vx > 0.f ? vx : 0.f;
    vy = vy > 0.f ? vy : 0.f;
    union { __hip_bfloat16 b[2]; unsigned int u; } cv;
    cv.b[0] = __float2bfloat16(vx); cv.b[1] = __float2bfloat16(vy);
    *(unsigned int*)((unsigned short*)hb + (size_t)node * HIDD + gc) = cv.u;
}

// ---------- parallel pooling from bf16 activations ----------
__global__ void k_pool2(const __hip_bfloat16* __restrict__ hb, const int* __restrict__ batch,
                        float* __restrict__ partial) {
    int g = blockIdx.x, i = blockIdx.y, col = threadIdx.x;
    int lo = lower_bound_i(batch, NN, g);
    int hi = lower_bound_i(batch, NN, g + 1);
    int len = hi - lo;
    int a = lo + (int)((long)len * i / PSPLIT);
    int b = lo + (int)((long)len * (i + 1) / PSPLIT);
    float acc = 0.f;
    const unsigned short* hu = (const unsigned short*)hb;
    for (int n = a; n < b; ++n) acc += bf2f(hu[(size_t)n * HIDD + col]);
    partial[((size_t)g * PSPLIT + i) * HIDD + col] = acc;
}

// ---------- final: sum partials + BN + FC ----------
__global__ __launch_bounds__(64) void k_final(const float* __restrict__ partial,
                                              const float* __restrict__ lg,
                                              const float* __restrict__ lb,
                                              const float* __restrict__ lm,
                                              const float* __restrict__ lv,
                                              const float* __restrict__ fcW,
                                              const float* __restrict__ fcb,
                                              float* __restrict__ out) {
    __shared__ float ps[HIDD];
    int g = blockIdx.x, j = threadIdx.x;
    for (int k = j; k < HIDD; k += 64) {
        float s = 0.f;
        for (int i = 0; i < PSPLIT; ++i)
            s += partial[((size_t)g * PSPLIT + i) * HIDD + k];
        ps[k] = (s - lm[k]) * rsqrtf(lv[k] + BNEPS) * lg[k] + lb[k];
    }
    __syncthreads();
    float acc = 0.f;
    for (int k = 0; k < HIDD; ++k)
        acc = fmaf(ps[k], fcW[k * LATD + j], acc);
    out[g * LATD + j] = acc + fcb[j];
}

extern "C" void kernel_launch(void* const* d_in, const int* in_sizes, int n_in,
                              void* d_out, int out_size, void* d_ws, size_t ws_size,
                              hipStream_t stream) {
    const float* x     = (const float*)d_in[0];
    const int*   ei    = (const int*)d_in[1];
    const int*   batch = (const int*)d_in[2];
    const float* W0    = (const float*)d_in[3];
    const float* Wr    = (const float*)d_in[4];
    const float* asrc  = (const float*)d_in[5];
    const float* adst  = (const float*)d_in[6];
    const float* bconv = (const float*)d_in[7];
    const float* bng   = (const float*)d_in[8];
    const float* bnb   = (const float*)d_in[9];
    const float* bnm   = (const float*)d_in[10];
    const float* bnv   = (const float*)d_in[11];
    const float* lg    = (const float*)d_in[12];
    const float* lb    = (const float*)d_in[13];
    const float* lm    = (const float*)d_in[14];
    const float* lv    = (const float*)d_in[15];
    const float* fcW   = (const float*)d_in[16];
    const float* fcb   = (const float*)d_in[17];
    float* out = (float*)d_out;

    char* w = (char*)d_ws;
    size_t off = 0;
    auto alloc = [&](size_t bytes) {
        char* p = w + off;
        off += (bytes + 255) / 256 * 256;
        return p;
    };
    float* al_s  = (float*)alloc((size_t)MPAD * NH * 4);
    float* al_d  = (float*)alloc((size_t)MPAD * NH * 4);
    float* partial = (float*)alloc((size_t)NG * PSPLIT * HIDD * 4);
    __hip_bfloat16* hbx = (__hip_bfloat16*)alloc((size_t)MPAD * IND * 2);    // bf16 x
    __hip_bfloat16* hb2 = (__hip_bfloat16*)alloc((size_t)MPAD * HIDD * 2);   // bf16 activations
    __hip_bfloat16* xpb2 = (__hip_bfloat16*)alloc((size_t)2 * MPAD * 128 * 2); // bf16 xp, ch-half sliced
    __hip_bfloat16* Wt3 = (__hip_bfloat16*)alloc(((size_t)HIDD * IND + 2 * (size_t)HIDD * HIDD) * 2);
    int* deg     = (int*)alloc((size_t)NN * 4);
    int* row_ptr = (int*)alloc((size_t)(NN + 1) * 4);
    int* cursor  = (int*)alloc((size_t)NN * 4);
    int* col_idx = (int*)alloc((size_t)EE * 4);
    int* bsum    = (int*)alloc((size_t)NB * 4);
    int* boff    = (int*)alloc((size_t)NB * 4);

    // ---- CSR build (dst-sorted edges) ----
    hipLaunchKernelGGL(k_zero, dim3(NB), dim3(256), 0, stream, deg, NN);
    hipLaunchKernelGGL(k_hist, dim3((EE + 255) / 256), dim3(256), 0, stream, ei, deg);
    hipLaunchKernelGGL(k_blocksum, dim3(NB), dim3(256), 0, stream, deg, bsum);
    hipLaunchKernelGGL(k_scanbs, dim3(1), dim3(128), 0, stream, bsum, boff, row_ptr);
    hipLaunchKernelGGL(k_scanapply, dim3(NB), dim3(256), 0, stream, deg, boff, row_ptr, cursor);
    hipLaunchKernelGGL(k_csr_scatter, dim3((EE + 255) / 256), dim3(256), 0, stream,
                       ei, cursor, col_idx);

    hipLaunchKernelGGL(k_cast_x, dim3((NN * IND / 4 + 255) / 256), dim3(256), 0, stream, x, hbx);
    hipLaunchKernelGGL(k_cast_wt_all, dim3(HIDD, 3), dim3(HIDD), 0, stream, W0, Wr, Wt3);

    const size_t wtoff[3] = {0, (size_t)HIDD * IND, (size_t)HIDD * IND + (size_t)HIDD * HIDD};

    for (int layer = 0; layer < 3; ++layer) {
        int K = (layer == 0) ? IND : HIDD;
        const __hip_bfloat16* Ab = (layer == 0) ? hbx : hb2;

        hipLaunchKernelGGL(k_gemm, dim3(MPAD / BM, HIDD / BN), dim3(256), 0, stream,
                           (const short*)Ab, (const short*)(Wt3 + wtoff[layer]), K, xpb2,
                           asrc + layer * NH * NC, adst + layer * NH * NC, al_s, al_d);
        // two sequential channel-half dispatches: each gathers from a 5.15 MB table
        for (int slice = 0; slice < 2; ++slice) {
            hipLaunchKernelGGL(k_gat_agg2, dim3((NN + 3) / 4), dim3(256), 0, stream,
                               row_ptr, col_idx, al_s, al_d,
                               xpb2 + (size_t)slice * MPAD * 128,
                               bconv + layer * HIDD, bng + layer * HIDD, bnb + layer * HIDD,
                               bnm + layer * HIDD, bnv + layer * HIDD, hb2, slice);
        }
    }

    hipLaunchKernelGGL(k_pool2, dim3(NG, PSPLIT), dim3(HIDD), 0, stream, hb2, batch, partial);
    hipLaunchKernelGGL(k_final, dim3(NG), dim3(LATD), 0, stream,
                       partial, lg, lb, lm, lv, fcW, fcb, out);
}

// Round 13
// 206.956 us; speedup vs baseline: 1.1821x; 1.1821x over previous
//
#include <hip/hip_runtime.h>
#include <hip/hip_bf16.h>
#include <cmath>

#define NN   20000              // nodes
#define NE   320000             // raw edges
#define EE   (NE + NN)          // edges incl. self-loops
#define NG   64                 // graphs
#define NH   4                  // heads
#define NC   64                 // channels/head
#define HIDD 256                // NH*NC
#define IND  128                // input feature dim
#define LATD 64                 // latent dim
#define NEGS 0.2f
#define BNEPS 1e-5f
#define MPAD 20096              // 157 * 128 (GEMM M padding)
#define PSPLIT 16               // pooling chunks per graph
#define NB   ((NN + 255) / 256) // scan blocks (79)

// GEMM tile
#define BM 128
#define BN 64
#define BK 64

typedef __attribute__((ext_vector_type(8))) short short8;
typedef __attribute__((ext_vector_type(4))) float f32x4;

__device__ inline int lower_bound_i(const int* __restrict__ b, int n, int key) {
    int lo = 0, hi = n;
    while (lo < hi) { int mid = (lo + hi) >> 1; if (b[mid] < key) lo = mid + 1; else hi = mid; }
    return lo;
}

__device__ inline float sel4(float4 v, int h) {
    float r = v.x;
    r = (h == 1) ? v.y : r;
    r = (h == 2) ? v.z : r;
    r = (h == 3) ? v.w : r;
    return r;
}

__device__ inline float bf2f(unsigned short u) {
    return __uint_as_float(((unsigned int)u) << 16);
}

__global__ void k_zero(int* __restrict__ p, int n) {
    int i = blockIdx.x * blockDim.x + threadIdx.x;
    if (i < n) p[i] = 0;
}

// ---------- fp32 -> bf16 cast of x ----------
__global__ void k_cast_x(const float* __restrict__ x, __hip_bfloat16* __restrict__ hbx) {
    int i = blockIdx.x * blockDim.x + threadIdx.x;     // over NN*IND/4
    if (i >= NN * IND / 4) return;
    float4 v = ((const float4*)x)[i];
    union { __hip_bfloat16 b[4]; ushort4 u; } cv;
    cv.b[0] = __float2bfloat16(v.x); cv.b[1] = __float2bfloat16(v.y);
    cv.b[2] = __float2bfloat16(v.z); cv.b[3] = __float2bfloat16(v.w);
    ((ushort4*)hbx)[i] = cv.u;
}

// ---------- all 3 layers: W[K][256] -> Wt[256][K] bf16, one dispatch ----------
__global__ void k_cast_wt_all(const float* __restrict__ W0, const float* __restrict__ Wr,
                              __hip_bfloat16* __restrict__ Wt3) {
    int k = blockIdx.x;          // 0..255
    int l = blockIdx.y;          // layer
    int n = threadIdx.x;         // 256
    int K = (l == 0) ? IND : HIDD;
    if (k >= K) return;
    const float* W = (l == 0) ? W0 : (Wr + (size_t)(l - 1) * HIDD * HIDD);
    size_t off = (l == 0) ? 0 : ((size_t)HIDD * IND + (size_t)(l - 1) * HIDD * HIDD);
    Wt3[off + (size_t)n * K + k] = __float2bfloat16(W[(size_t)k * HIDD + n]);
}

// ---------- CSR build ----------
__global__ void k_hist(const int* __restrict__ ei, int* __restrict__ deg) {
    int e = blockIdx.x * blockDim.x + threadIdx.x;
    if (e >= EE) return;
    int d = (e < NE) ? ei[NE + e] : (e - NE);
    atomicAdd(&deg[d], 1);
}

__global__ __launch_bounds__(256) void k_blocksum(const int* __restrict__ deg,
                                                  int* __restrict__ bsum) {
    __shared__ int s[256];
    int i = blockIdx.x * 256 + threadIdx.x;
    s[threadIdx.x] = (i < NN) ? deg[i] : 0;
    __syncthreads();
    for (int off = 128; off > 0; off >>= 1) {
        if (threadIdx.x < off) s[threadIdx.x] += s[threadIdx.x + off];
        __syncthreads();
    }
    if (threadIdx.x == 0) bsum[blockIdx.x] = s[0];
}

__global__ __launch_bounds__(128) void k_scanbs(const int* __restrict__ bsum,
                                                int* __restrict__ boff,
                                                int* __restrict__ row_ptr) {
    __shared__ int s[128];
    int tid = threadIdx.x;
    int v = (tid < NB) ? bsum[tid] : 0;
    s[tid] = v;
    __syncthreads();
    for (int off = 1; off < 128; off <<= 1) {
        int t = (tid >= off) ? s[tid - off] : 0;
        __syncthreads();
        s[tid] += t;
        __syncthreads();
    }
    if (tid < NB) boff[tid] = s[tid] - v;          // exclusive block offset
    if (tid == NB - 1) row_ptr[NN] = s[tid];       // total (= EE)
}

__global__ __launch_bounds__(256) void k_scanapply(const int* __restrict__ deg,
                                                   const int* __restrict__ boff,
                                                   int* __restrict__ row_ptr,
                                                   int* __restrict__ cursor) {
    __shared__ int s[256];
    int i = blockIdx.x * 256 + threadIdx.x;
    int v = (i < NN) ? deg[i] : 0;
    s[threadIdx.x] = v;
    __syncthreads();
    for (int off = 1; off < 256; off <<= 1) {
        int t = (threadIdx.x >= off) ? s[threadIdx.x - off] : 0;
        __syncthreads();
        s[threadIdx.x] += t;
        __syncthreads();
    }
    if (i < NN) {
        int excl = boff[blockIdx.x] + s[threadIdx.x] - v;
        row_ptr[i] = excl; cursor[i] = excl;
    }
}

__global__ void k_csr_scatter(const int* __restrict__ ei, int* __restrict__ cursor,
                              int* __restrict__ col_idx) {
    int e = blockIdx.x * blockDim.x + threadIdx.x;
    if (e >= EE) return;
    int s, d;
    if (e < NE) { s = ei[e]; d = ei[NE + e]; } else { s = d = e - NE; }
    int pos = atomicAdd(&cursor[d], 1);
    col_idx[pos] = s;
}

// ---------- MFMA GEMM + fused attention scalars ----------
__global__ __launch_bounds__(256) void k_gemm(const short* __restrict__ A,
                                              const short* __restrict__ Bt,
                                              int K, __hip_bfloat16* __restrict__ Cb,
                                              const float* __restrict__ a_src,
                                              const float* __restrict__ a_dst,
                                              float* __restrict__ al_s,
                                              float* __restrict__ al_d) {
    __shared__ char As[BM * BK * 2];   // 16 KB, XOR-swizzled
    __shared__ char Bs[BN * BK * 2];   // 8 KB
    __shared__ float redS[2][BM];      // 1 KB
    __shared__ float redD[2][BM];      // 1 KB
    int tid = threadIdx.x;
    int lane = tid & 63;
    int wid = tid >> 6;
    int wm = wid >> 1, wn = wid & 1;               // 2x2 wave grid
    int bm0 = blockIdx.x * BM, bn0 = blockIdx.y * BN;
    int r16 = lane & 15, kg = lane >> 4;

    f32x4 acc[4][2];
    #pragma unroll
    for (int m = 0; m < 4; ++m)
        #pragma unroll
        for (int n = 0; n < 2; ++n) acc[m][n] = (f32x4){0.f, 0.f, 0.f, 0.f};

    for (int k0 = 0; k0 < K; k0 += BK) {
        __syncthreads();
        #pragma unroll
        for (int p = 0; p < 4; ++p) {
            int row = p * 32 + (tid >> 3);
            int cg  = tid & 7;
            uint4 v = *(const uint4*)(A + (size_t)(bm0 + row) * K + k0 + cg * 8);
            *(uint4*)(As + row * 128 + ((cg * 16) ^ ((row & 7) << 4))) = v;
        }
        #pragma unroll
        for (int p = 0; p < 2; ++p) {
            int row = p * 32 + (tid >> 3);
            int cg  = tid & 7;
            uint4 v = *(const uint4*)(Bt + (size_t)(bn0 + row) * K + k0 + cg * 8);
            *(uint4*)(Bs + row * 128 + ((cg * 16) ^ ((row & 7) << 4))) = v;
        }
        __syncthreads();
        #pragma unroll
        for (int kk = 0; kk < 2; ++kk) {
            short8 af[4], bfr[2];
            int kb = (kk * 32 + kg * 8) * 2;
            #pragma unroll
            for (int m = 0; m < 4; ++m) {
                int row = wm * 64 + m * 16 + r16;
                af[m] = *(const short8*)(As + row * 128 + (kb ^ ((row & 7) << 4)));
            }
            #pragma unroll
            for (int n = 0; n < 2; ++n) {
                int row = wn * 32 + n * 16 + r16;
                bfr[n] = *(const short8*)(Bs + row * 128 + (kb ^ ((row & 7) << 4)));
            }
            #pragma unroll
            for (int m = 0; m < 4; ++m)
                #pragma unroll
                for (int n = 0; n < 2; ++n)
                    acc[m][n] = __builtin_amdgcn_mfma_f32_16x16x32_bf16(af[m], bfr[n], acc[m][n], 0, 0, 0);
        }
    }

    // ---- C store (bf16) ----
    #pragma unroll
    for (int m = 0; m < 4; ++m) {
        int row = bm0 + wm * 64 + m * 16 + kg * 4;
        #pragma unroll
        for (int n = 0; n < 2; ++n) {
            int col = bn0 + wn * 32 + n * 16 + r16;
            #pragma unroll
            for (int r = 0; r < 4; ++r)
                Cb[(size_t)(row + r) * HIDD + col] = __float2bfloat16(acc[m][n][r]);
        }
    }

    // ---- fused attention scalars: al_s/al_d[row][head=blockIdx.y] ----
    int headbase = bn0;                              // = blockIdx.y * 64
    float as0 = a_src[headbase + wn * 32 + r16];
    float as1 = a_src[headbase + wn * 32 + 16 + r16];
    float ad0 = a_dst[headbase + wn * 32 + r16];
    float ad1 = a_dst[headbase + wn * 32 + 16 + r16];
    #pragma unroll
    for (int m = 0; m < 4; ++m) {
        #pragma unroll
        for (int r = 0; r < 4; ++r) {
            float ps = as0 * acc[m][0][r] + as1 * acc[m][1][r];
            float pd = ad0 * acc[m][0][r] + ad1 * acc[m][1][r];
            #pragma unroll
            for (int msk = 1; msk < 16; msk <<= 1) {
                ps += __shfl_xor(ps, msk, 64);
                pd += __shfl_xor(pd, msk, 64);
            }
            if (r16 == 0) {
                int rl = wm * 64 + m * 16 + kg * 4 + r;
                redS[wn][rl] = ps;
                redD[wn][rl] = pd;
            }
        }
    }
    __syncthreads();
    if (tid < BM) {
        int node = bm0 + tid;
        al_s[node * NH + blockIdx.y] = redS[0][tid] + redS[1][tid];
        al_d[node * NH + blockIdx.y] = redD[0][tid] + redD[1][tid];
    }
}

// ---------- fused single-pass edge-softmax + bf16 gather-aggregate + bias/BN/ReLU ----------
// wave per node; 8 gathers in flight per iteration, shared 4 acc/den chains
#define EDGE_BODY(I, J) \
    { float l = as##I + adh; l = l > 0.f ? l : NEGS * l; \
      float wt = __expf(l); den##J += wt; \
      acc##J.x = fmaf(wt, bf2f(xv##I.x), acc##J.x); \
      acc##J.y = fmaf(wt, bf2f(xv##I.y), acc##J.y); \
      acc##J.z = fmaf(wt, bf2f(xv##I.z), acc##J.z); \
      acc##J.w = fmaf(wt, bf2f(xv##I.w), acc##J.w); }

__global__ __launch_bounds__(256) void k_gat_agg(
        const int* __restrict__ row_ptr, const int* __restrict__ col_idx,
        const float* __restrict__ al_s, const float* __restrict__ al_d,
        const __hip_bfloat16* __restrict__ xpb,
        const float* __restrict__ bias, const float* __restrict__ bg,
        const float* __restrict__ bb, const float* __restrict__ bm,
        const float* __restrict__ bv,
        __hip_bfloat16* __restrict__ hb) {
    int wid = threadIdx.x >> 6, lane = threadIdx.x & 63;
    int node = blockIdx.x * 4 + wid;
    if (node >= NN) return;
    int lo = row_ptr[node], hi = row_ptr[node + 1];
    int hsel = lane >> 4;
    float adh = sel4(((const float4*)al_d)[node], hsel);

    float4 acc0 = {0,0,0,0}, acc1 = {0,0,0,0}, acc2 = {0,0,0,0}, acc3 = {0,0,0,0};
    float den0 = 0.f, den1 = 0.f, den2 = 0.f, den3 = 0.f;

    int e = lo;
    for (; e + 7 < hi; e += 8) {
        int sc0 = col_idx[e],     sc1 = col_idx[e + 1], sc2 = col_idx[e + 2], sc3 = col_idx[e + 3];
        int sc4 = col_idx[e + 4], sc5 = col_idx[e + 5], sc6 = col_idx[e + 6], sc7 = col_idx[e + 7];
        float as0 = al_s[sc0 * NH + hsel], as1 = al_s[sc1 * NH + hsel];
        float as2 = al_s[sc2 * NH + hsel], as3 = al_s[sc3 * NH + hsel];
        float as4 = al_s[sc4 * NH + hsel], as5 = al_s[sc5 * NH + hsel];
        float as6 = al_s[sc6 * NH + hsel], as7 = al_s[sc7 * NH + hsel];
        ushort4 xv0 = ((const ushort4*)(xpb + (size_t)sc0 * HIDD))[lane];
        ushort4 xv1 = ((const ushort4*)(xpb + (size_t)sc1 * HIDD))[lane];
        ushort4 xv2 = ((const ushort4*)(xpb + (size_t)sc2 * HIDD))[lane];
        ushort4 xv3 = ((const ushort4*)(xpb + (size_t)sc3 * HIDD))[lane];
        ushort4 xv4 = ((const ushort4*)(xpb + (size_t)sc4 * HIDD))[lane];
        ushort4 xv5 = ((const ushort4*)(xpb + (size_t)sc5 * HIDD))[lane];
        ushort4 xv6 = ((const ushort4*)(xpb + (size_t)sc6 * HIDD))[lane];
        ushort4 xv7 = ((const ushort4*)(xpb + (size_t)sc7 * HIDD))[lane];
        EDGE_BODY(0, 0) EDGE_BODY(1, 1) EDGE_BODY(2, 2) EDGE_BODY(3, 3)
        EDGE_BODY(4, 0) EDGE_BODY(5, 1) EDGE_BODY(6, 2) EDGE_BODY(7, 3)
    }
    if (e + 3 < hi) {
        int sc0 = col_idx[e], sc1 = col_idx[e + 1], sc2 = col_idx[e + 2], sc3 = col_idx[e + 3];
        float as0 = al_s[sc0 * NH + hsel], as1 = al_s[sc1 * NH + hsel];
        float as2 = al_s[sc2 * NH + hsel], as3 = al_s[sc3 * NH + hsel];
        ushort4 xv0 = ((const ushort4*)(xpb + (size_t)sc0 * HIDD))[lane];
        ushort4 xv1 = ((const ushort4*)(xpb + (size_t)sc1 * HIDD))[lane];
        ushort4 xv2 = ((const ushort4*)(xpb + (size_t)sc2 * HIDD))[lane];
        ushort4 xv3 = ((const ushort4*)(xpb + (size_t)sc3 * HIDD))[lane];
        EDGE_BODY(0, 0) EDGE_BODY(1, 1) EDGE_BODY(2, 2) EDGE_BODY(3, 3)
        e += 4;
    }
    for (; e < hi; ++e) {
        int sc0 = col_idx[e];
        float as0 = al_s[sc0 * NH + hsel];
        ushort4 xv0 = ((const ushort4*)(xpb + (size_t)sc0 * HIDD))[lane];
        EDGE_BODY(0, 0)
    }

    float den = (den0 + den1) + (den2 + den3);
    float inv = 1.f / (den + 1e-16f);
    float4 acc;
    acc.x = ((acc0.x + acc1.x) + (acc2.x + acc3.x)) * inv;
    acc.y = ((acc0.y + acc1.y) + (acc2.y + acc3.y)) * inv;
    acc.z = ((acc0.z + acc1.z) + (acc2.z + acc3.z)) * inv;
    acc.w = ((acc0.w + acc1.w) + (acc2.w + acc3.w)) * inv;

    // epilogue: bias + BN(eval) + ReLU, bf16 store
    float4 bi = ((const float4*)bias)[lane];
    float4 gg = ((const float4*)bg)[lane];
    float4 be = ((const float4*)bb)[lane];
    float4 mn = ((const float4*)bm)[lane];
    float4 vr = ((const float4*)bv)[lane];
    float4 val;
    val.x = (acc.x + bi.x - mn.x) * rsqrtf(vr.x + BNEPS) * gg.x + be.x;
    val.y = (acc.y + bi.y - mn.y) * rsqrtf(vr.y + BNEPS) * gg.y + be.y;
    val.z = (acc.z + bi.z - mn.z) * rsqrtf(vr.z + BNEPS) * gg.z + be.z;
    val.w = (acc.w + bi.w - mn.w) * rsqrtf(vr.w + BNEPS) * gg.w + be.w;
    val.x = val.x > 0.f ? val.x : 0.f;
    val.y = val.y > 0.f ? val.y : 0.f;
    val.z = val.z > 0.f ? val.z : 0.f;
    val.w = val.w > 0.f ? val.w : 0.f;
    union { __hip_bfloat16 b[4]; ushort4 u; } cv;
    cv.b[0] = __float2bfloat16(val.x); cv.b[1] = __float2bfloat16(val.y);
    cv.b[2] = __float2bfloat16(val.z); cv.b[3] = __float2bfloat16(val.w);
    ((ushort4*)hb)[(size_t)node * 64 + lane] = cv.u;
}

// ---------- parallel pooling from bf16 activations ----------
__global__ void k_pool2(const __hip_bfloat16* __restrict__ hb, const int* __restrict__ batch,
                        float* __restrict__ partial) {
    int g = blockIdx.x, i = blockIdx.y, col = threadIdx.x;
    int lo = lower_bound_i(batch, NN, g);
    int hi = lower_bound_i(batch, NN, g + 1);
    int len = hi - lo;
    int a = lo + (int)((long)len * i / PSPLIT);
    int b = lo + (int)((long)len * (i + 1) / PSPLIT);
    float acc = 0.f;
    const unsigned short* hu = (const unsigned short*)hb;
    for (int n = a; n < b; ++n) acc += bf2f(hu[(size_t)n * HIDD + col]);
    partial[((size_t)g * PSPLIT + i) * HIDD + col] = acc;
}

// ---------- final: sum partials + BN + FC ----------
__global__ __launch_bounds__(64) void k_final(const float* __restrict__ partial,
                                              const float* __restrict__ lg,
                                              const float* __restrict__ lb,
                                              const float* __restrict__ lm,
                                              const float* __restrict__ lv,
                                              const float* __restrict__ fcW,
                                              const float* __restrict__ fcb,
                                              float* __restrict__ out) {
    __shared__ float ps[HIDD];
    int g = blockIdx.x, j = threadIdx.x;
    for (int k = j; k < HIDD; k += 64) {
        float s = 0.f;
        for (int i = 0; i < PSPLIT; ++i)
            s += partial[((size_t)g * PSPLIT + i) * HIDD + k];
        ps[k] = (s - lm[k]) * rsqrtf(lv[k] + BNEPS) * lg[k] + lb[k];
    }
    __syncthreads();
    float acc = 0.f;
    for (int k = 0; k < HIDD; ++k)
        acc = fmaf(ps[k], fcW[k * LATD + j], acc);
    out[g * LATD + j] = acc + fcb[j];
}

extern "C" void kernel_launch(void* const* d_in, const int* in_sizes, int n_in,
                              void* d_out, int out_size, void* d_ws, size_t ws_size,
                              hipStream_t stream) {
    const float* x     = (const float*)d_in[0];
    const int*   ei    = (const int*)d_in[1];
    const int*   batch = (const int*)d_in[2];
    const float* W0    = (const float*)d_in[3];
    const float* Wr    = (const float*)d_in[4];
    const float* asrc  = (const float*)d_in[5];
    const float* adst  = (const float*)d_in[6];
    const float* bconv = (const float*)d_in[7];
    const float* bng   = (const float*)d_in[8];
    const float* bnb   = (const float*)d_in[9];
    const float* bnm   = (const float*)d_in[10];
    const float* bnv   = (const float*)d_in[11];
    const float* lg    = (const float*)d_in[12];
    const float* lb    = (const float*)d_in[13];
    const float* lm    = (const float*)d_in[14];
    const float* lv    = (const float*)d_in[15];
    const float* fcW   = (const float*)d_in[16];
    const float* fcb   = (const float*)d_in[17];
    float* out = (float*)d_out;

    char* w = (char*)d_ws;
    size_t off = 0;
    auto alloc = [&](size_t bytes) {
        char* p = w + off;
        off += (bytes + 255) / 256 * 256;
        return p;
    };
    float* al_s  = (float*)alloc((size_t)MPAD * NH * 4);
    float* al_d  = (float*)alloc((size_t)MPAD * NH * 4);
    float* partial = (float*)alloc((size_t)NG * PSPLIT * HIDD * 4);
    __hip_bfloat16* hbx = (__hip_bfloat16*)alloc((size_t)MPAD * IND * 2);   // bf16 x
    __hip_bfloat16* hb2 = (__hip_bfloat16*)alloc((size_t)MPAD * HIDD * 2);  // bf16 activations
    __hip_bfloat16* xpb = (__hip_bfloat16*)alloc((size_t)MPAD * HIDD * 2);  // bf16 xp
    __hip_bfloat16* Wt3 = (__hip_bfloat16*)alloc(((size_t)HIDD * IND + 2 * (size_t)HIDD * HIDD) * 2);
    int* deg     = (int*)alloc((size_t)NN * 4);
    int* row_ptr = (int*)alloc((size_t)(NN + 1) * 4);
    int* cursor  = (int*)alloc((size_t)NN * 4);
    int* col_idx = (int*)alloc((size_t)EE * 4);
    int* bsum    = (int*)alloc((size_t)NB * 4);
    int* boff    = (int*)alloc((size_t)NB * 4);

    // ---- CSR build (dst-sorted edges) ----
    hipLaunchKernelGGL(k_zero, dim3(NB), dim3(256), 0, stream, deg, NN);
    hipLaunchKernelGGL(k_hist, dim3((EE + 255) / 256), dim3(256), 0, stream, ei, deg);
    hipLaunchKernelGGL(k_blocksum, dim3(NB), dim3(256), 0, stream, deg, bsum);
    hipLaunchKernelGGL(k_scanbs, dim3(1), dim3(128), 0, stream, bsum, boff, row_ptr);
    hipLaunchKernelGGL(k_scanapply, dim3(NB), dim3(256), 0, stream, deg, boff, row_ptr, cursor);
    hipLaunchKernelGGL(k_csr_scatter, dim3((EE + 255) / 256), dim3(256), 0, stream,
                       ei, cursor, col_idx);

    hipLaunchKernelGGL(k_cast_x, dim3((NN * IND / 4 + 255) / 256), dim3(256), 0, stream, x, hbx);
    hipLaunchKernelGGL(k_cast_wt_all, dim3(HIDD, 3), dim3(HIDD), 0, stream, W0, Wr, Wt3);

    const size_t wtoff[3] = {0, (size_t)HIDD * IND, (size_t)HIDD * IND + (size_t)HIDD * HIDD};

    for (int layer = 0; layer < 3; ++layer) {
        int K = (layer == 0) ? IND : HIDD;
        const __hip_bfloat16* Ab = (layer == 0) ? hbx : hb2;

        hipLaunchKernelGGL(k_gemm, dim3(MPAD / BM, HIDD / BN), dim3(256), 0, stream,
                           (const short*)Ab, (const short*)(Wt3 + wtoff[layer]), K, xpb,
                           asrc + layer * NH * NC, adst + layer * NH * NC, al_s, al_d);
        hipLaunchKernelGGL(k_gat_agg, dim3((NN + 3) / 4), dim3(256), 0, stream,
                           row_ptr, col_idx, al_s, al_d, xpb,
                           bconv + layer * HIDD, bng + layer * HIDD, bnb + layer * HIDD,
                           bnm + layer * HIDD, bnv + layer * HIDD, hb2);
    }

    hipLaunchKernelGGL(k_pool2, dim3(NG, PSPLIT), dim3(HIDD), 0, stream, hb2, batch, partial);
    hipLaunchKernelGGL(k_final, dim3(NG), dim3(LATD), 0, stream,
                       partial, lg, lb, lm, lv, fcW, fcb, out);
}

// Round 14
// 204.891 us; speedup vs baseline: 1.1940x; 1.0101x over previous
//
#include <hip/hip_runtime.h>
#include <hip/hip_bf16.h>
#include <cmath>

#define NN   20000              // nodes
#define NE   320000             // raw edges
#define EE   (NE + NN)          // edges incl. self-loops
#define NG   64                 // graphs
#define NH   4                  // heads
#define NC   64                 // channels/head
#define HIDD 256                // NH*NC
#define IND  128                // input feature dim
#define LATD 64                 // latent dim
#define NEGS 0.2f
#define BNEPS 1e-5f
#define MPAD 20096              // 157 * 128 (GEMM M padding)
#define PSPLIT 16               // pooling chunks per graph
#define NB   ((NN + 255) / 256) // scan blocks (79)

// GEMM tile
#define BM 128
#define BN 64
#define BK 64

typedef __attribute__((ext_vector_type(8))) short short8;
typedef __attribute__((ext_vector_type(4))) float f32x4;

__device__ inline int lower_bound_i(const int* __restrict__ b, int n, int key) {
    int lo = 0, hi = n;
    while (lo < hi) { int mid = (lo + hi) >> 1; if (b[mid] < key) lo = mid + 1; else hi = mid; }
    return lo;
}

__device__ inline float sel4(float4 v, int h) {
    float r = v.x;
    r = (h == 1) ? v.y : r;
    r = (h == 2) ? v.z : r;
    r = (h == 3) ? v.w : r;
    return r;
}

__device__ inline float bf2f(unsigned short u) {
    return __uint_as_float(((unsigned int)u) << 16);
}

__global__ void k_zero(int* __restrict__ p, int n) {
    int i = blockIdx.x * blockDim.x + threadIdx.x;
    if (i < n) p[i] = 0;
}

// ---------- fp32 -> bf16 cast of x ----------
__global__ void k_cast_x(const float* __restrict__ x, __hip_bfloat16* __restrict__ hbx) {
    int i = blockIdx.x * blockDim.x + threadIdx.x;     // over NN*IND/4
    if (i >= NN * IND / 4) return;
    float4 v = ((const float4*)x)[i];
    union { __hip_bfloat16 b[4]; ushort4 u; } cv;
    cv.b[0] = __float2bfloat16(v.x); cv.b[1] = __float2bfloat16(v.y);
    cv.b[2] = __float2bfloat16(v.z); cv.b[3] = __float2bfloat16(v.w);
    ((ushort4*)hbx)[i] = cv.u;
}

// ---------- all 3 layers: W[K][256] -> Wt[256][K] bf16, one dispatch ----------
__global__ void k_cast_wt_all(const float* __restrict__ W0, const float* __restrict__ Wr,
                              __hip_bfloat16* __restrict__ Wt3) {
    int k = blockIdx.x;          // 0..255
    int l = blockIdx.y;          // layer
    int n = threadIdx.x;         // 256
    int K = (l == 0) ? IND : HIDD;
    if (k >= K) return;
    const float* W = (l == 0) ? W0 : (Wr + (size_t)(l - 1) * HIDD * HIDD);
    size_t off = (l == 0) ? 0 : ((size_t)HIDD * IND + (size_t)(l - 1) * HIDD * HIDD);
    Wt3[off + (size_t)n * K + k] = __float2bfloat16(W[(size_t)k * HIDD + n]);
}

// ---------- CSR build ----------
__global__ void k_hist(const int* __restrict__ ei, int* __restrict__ deg) {
    int e = blockIdx.x * blockDim.x + threadIdx.x;
    if (e >= EE) return;
    int d = (e < NE) ? ei[NE + e] : (e - NE);
    atomicAdd(&deg[d], 1);
}

__global__ __launch_bounds__(256) void k_blocksum(const int* __restrict__ deg,
                                                  int* __restrict__ bsum) {
    __shared__ int s[256];
    int i = blockIdx.x * 256 + threadIdx.x;
    s[threadIdx.x] = (i < NN) ? deg[i] : 0;
    __syncthreads();
    for (int off = 128; off > 0; off >>= 1) {
        if (threadIdx.x < off) s[threadIdx.x] += s[threadIdx.x + off];
        __syncthreads();
    }
    if (threadIdx.x == 0) bsum[blockIdx.x] = s[0];
}

__global__ __launch_bounds__(128) void k_scanbs(const int* __restrict__ bsum,
                                                int* __restrict__ boff,
                                                int* __restrict__ row_ptr) {
    __shared__ int s[128];
    int tid = threadIdx.x;
    int v = (tid < NB) ? bsum[tid] : 0;
    s[tid] = v;
    __syncthreads();
    for (int off = 1; off < 128; off <<= 1) {
        int t = (tid >= off) ? s[tid - off] : 0;
        __syncthreads();
        s[tid] += t;
        __syncthreads();
    }
    if (tid < NB) boff[tid] = s[tid] - v;          // exclusive block offset
    if (tid == NB - 1) row_ptr[NN] = s[tid];       // total (= EE)
}

__global__ __launch_bounds__(256) void k_scanapply(const int* __restrict__ deg,
                                                   const int* __restrict__ boff,
                                                   int* __restrict__ row_ptr,
                                                   int* __restrict__ cursor) {
    __shared__ int s[256];
    int i = blockIdx.x * 256 + threadIdx.x;
    int v = (i < NN) ? deg[i] : 0;
    s[threadIdx.x] = v;
    __syncthreads();
    for (int off = 1; off < 256; off <<= 1) {
        int t = (threadIdx.x >= off) ? s[threadIdx.x - off] : 0;
        __syncthreads();
        s[threadIdx.x] += t;
        __syncthreads();
    }
    if (i < NN) {
        int excl = boff[blockIdx.x] + s[threadIdx.x] - v;
        row_ptr[i] = excl; cursor[i] = excl;
    }
}

__global__ void k_csr_scatter(const int* __restrict__ ei, int* __restrict__ cursor,
                              int* __restrict__ col_idx) {
    int e = blockIdx.x * blockDim.x + threadIdx.x;
    if (e >= EE) return;
    int s, d;
    if (e < NE) { s = ei[e]; d = ei[NE + e]; } else { s = d = e - NE; }
    int pos = atomicAdd(&cursor[d], 1);
    col_idx[pos] = s;
}

// ---------- MFMA GEMM + fused attention scalars ----------
__global__ __launch_bounds__(256) void k_gemm(const short* __restrict__ A,
                                              const short* __restrict__ Bt,
                                              int K, __hip_bfloat16* __restrict__ Cb,
                                              const float* __restrict__ a_src,
                                              const float* __restrict__ a_dst,
                                              float* __restrict__ al_s,
                                              float* __restrict__ al_d) {
    __shared__ char As[BM * BK * 2];   // 16 KB, XOR-swizzled
    __shared__ char Bs[BN * BK * 2];   // 8 KB
    __shared__ float redS[2][BM];      // 1 KB
    __shared__ float redD[2][BM];      // 1 KB
    int tid = threadIdx.x;
    int lane = tid & 63;
    int wid = tid >> 6;
    int wm = wid >> 1, wn = wid & 1;               // 2x2 wave grid
    int bm0 = blockIdx.x * BM, bn0 = blockIdx.y * BN;
    int r16 = lane & 15, kg = lane >> 4;

    f32x4 acc[4][2];
    #pragma unroll
    for (int m = 0; m < 4; ++m)
        #pragma unroll
        for (int n = 0; n < 2; ++n) acc[m][n] = (f32x4){0.f, 0.f, 0.f, 0.f};

    for (int k0 = 0; k0 < K; k0 += BK) {
        __syncthreads();
        #pragma unroll
        for (int p = 0; p < 4; ++p) {
            int row = p * 32 + (tid >> 3);
            int cg  = tid & 7;
            uint4 v = *(const uint4*)(A + (size_t)(bm0 + row) * K + k0 + cg * 8);
            *(uint4*)(As + row * 128 + ((cg * 16) ^ ((row & 7) << 4))) = v;
        }
        #pragma unroll
        for (int p = 0; p < 2; ++p) {
            int row = p * 32 + (tid >> 3);
            int cg  = tid & 7;
            uint4 v = *(const uint4*)(Bt + (size_t)(bn0 + row) * K + k0 + cg * 8);
            *(uint4*)(Bs + row * 128 + ((cg * 16) ^ ((row & 7) << 4))) = v;
        }
        __syncthreads();
        #pragma unroll
        for (int kk = 0; kk < 2; ++kk) {
            short8 af[4], bfr[2];
            int kb = (kk * 32 + kg * 8) * 2;
            #pragma unroll
            for (int m = 0; m < 4; ++m) {
                int row = wm * 64 + m * 16 + r16;
                af[m] = *(const short8*)(As + row * 128 + (kb ^ ((row & 7) << 4)));
            }
            #pragma unroll
            for (int n = 0; n < 2; ++n) {
                int row = wn * 32 + n * 16 + r16;
                bfr[n] = *(const short8*)(Bs + row * 128 + (kb ^ ((row & 7) << 4)));
            }
            #pragma unroll
            for (int m = 0; m < 4; ++m)
                #pragma unroll
                for (int n = 0; n < 2; ++n)
                    acc[m][n] = __builtin_amdgcn_mfma_f32_16x16x32_bf16(af[m], bfr[n], acc[m][n], 0, 0, 0);
        }
    }

    // ---- C store (bf16) ----
    #pragma unroll
    for (int m = 0; m < 4; ++m) {
        int row = bm0 + wm * 64 + m * 16 + kg * 4;
        #pragma unroll
        for (int n = 0; n < 2; ++n) {
            int col = bn0 + wn * 32 + n * 16 + r16;
            #pragma unroll
            for (int r = 0; r < 4; ++r)
                Cb[(size_t)(row + r) * HIDD + col] = __float2bfloat16(acc[m][n][r]);
        }
    }

    // ---- fused attention scalars: al_s/al_d[row][head=blockIdx.y] ----
    int headbase = bn0;                              // = blockIdx.y * 64
    float as0 = a_src[headbase + wn * 32 + r16];
    float as1 = a_src[headbase + wn * 32 + 16 + r16];
    float ad0 = a_dst[headbase + wn * 32 + r16];
    float ad1 = a_dst[headbase + wn * 32 + 16 + r16];
    #pragma unroll
    for (int m = 0; m < 4; ++m) {
        #pragma unroll
        for (int r = 0; r < 4; ++r) {
            float ps = as0 * acc[m][0][r] + as1 * acc[m][1][r];
            float pd = ad0 * acc[m][0][r] + ad1 * acc[m][1][r];
            #pragma unroll
            for (int msk = 1; msk < 16; msk <<= 1) {
                ps += __shfl_xor(ps, msk, 64);
                pd += __shfl_xor(pd, msk, 64);
            }
            if (r16 == 0) {
                int rl = wm * 64 + m * 16 + kg * 4 + r;
                redS[wn][rl] = ps;
                redD[wn][rl] = pd;
            }
        }
    }
    __syncthreads();
    if (tid < BM) {
        int node = bm0 + tid;
        al_s[node * NH + blockIdx.y] = redS[0][tid] + redS[1][tid];
        al_d[node * NH + blockIdx.y] = redD[0][tid] + redD[1][tid];
    }
}

// ---------- fused single-pass edge-softmax + bf16 gather-aggregate + bias/BN/ReLU ----------
// wave per node, unroll-4 (best measured: R6); col_idx via readfirstlane (scalar loads)
#define EDGE_BODY(I) \
    { float l = as##I + adh; l = l > 0.f ? l : NEGS * l; \
      float wt = __expf(l); den##I += wt; \
      acc##I.x = fmaf(wt, bf2f(xv##I.x), acc##I.x); \
      acc##I.y = fmaf(wt, bf2f(xv##I.y), acc##I.y); \
      acc##I.z = fmaf(wt, bf2f(xv##I.z), acc##I.z); \
      acc##I.w = fmaf(wt, bf2f(xv##I.w), acc##I.w); }

__global__ __launch_bounds__(256) void k_gat_agg(
        const int* __restrict__ row_ptr, const int* __restrict__ col_idx,
        const float* __restrict__ al_s, const float* __restrict__ al_d,
        const __hip_bfloat16* __restrict__ xpb,
        const float* __restrict__ bias, const float* __restrict__ bg,
        const float* __restrict__ bb, const float* __restrict__ bm,
        const float* __restrict__ bv,
        __hip_bfloat16* __restrict__ hb) {
    int wid = threadIdx.x >> 6, lane = threadIdx.x & 63;
    int node = blockIdx.x * 4 + wid;
    if (node >= NN) return;
    int lo = row_ptr[node], hi = row_ptr[node + 1];
    int hsel = lane >> 4;
    float adh = sel4(((const float4*)al_d)[node], hsel);

    float4 acc0 = {0,0,0,0}, acc1 = {0,0,0,0}, acc2 = {0,0,0,0}, acc3 = {0,0,0,0};
    float den0 = 0.f, den1 = 0.f, den2 = 0.f, den3 = 0.f;

    int e = lo;
    for (; e + 3 < hi; e += 4) {
        int sc0 = __builtin_amdgcn_readfirstlane(col_idx[e]);
        int sc1 = __builtin_amdgcn_readfirstlane(col_idx[e + 1]);
        int sc2 = __builtin_amdgcn_readfirstlane(col_idx[e + 2]);
        int sc3 = __builtin_amdgcn_readfirstlane(col_idx[e + 3]);
        float as0 = al_s[sc0 * NH + hsel];
        float as1 = al_s[sc1 * NH + hsel];
        float as2 = al_s[sc2 * NH + hsel];
        float as3 = al_s[sc3 * NH + hsel];
        ushort4 xv0 = ((const ushort4*)(xpb + (size_t)sc0 * HIDD))[lane];
        ushort4 xv1 = ((const ushort4*)(xpb + (size_t)sc1 * HIDD))[lane];
        ushort4 xv2 = ((const ushort4*)(xpb + (size_t)sc2 * HIDD))[lane];
        ushort4 xv3 = ((const ushort4*)(xpb + (size_t)sc3 * HIDD))[lane];
        EDGE_BODY(0) EDGE_BODY(1) EDGE_BODY(2) EDGE_BODY(3)
    }
    for (; e < hi; ++e) {
        int sc0 = __builtin_amdgcn_readfirstlane(col_idx[e]);
        float as0 = al_s[sc0 * NH + hsel];
        ushort4 xv0 = ((const ushort4*)(xpb + (size_t)sc0 * HIDD))[lane];
        EDGE_BODY(0)
    }

    float den = (den0 + den1) + (den2 + den3);
    float inv = 1.f / (den + 1e-16f);
    float4 acc;
    acc.x = ((acc0.x + acc1.x) + (acc2.x + acc3.x)) * inv;
    acc.y = ((acc0.y + acc1.y) + (acc2.y + acc3.y)) * inv;
    acc.z = ((acc0.z + acc1.z) + (acc2.z + acc3.z)) * inv;
    acc.w = ((acc0.w + acc1.w) + (acc2.w + acc3.w)) * inv;

    // epilogue: bias + BN(eval) + ReLU, bf16 store
    float4 bi = ((const float4*)bias)[lane];
    float4 gg = ((const float4*)bg)[lane];
    float4 be = ((const float4*)bb)[lane];
    float4 mn = ((const float4*)bm)[lane];
    float4 vr = ((const float4*)bv)[lane];
    float4 val;
    val.x = (acc.x + bi.x - mn.x) * rsqrtf(vr.x + BNEPS) * gg.x + be.x;
    val.y = (acc.y + bi.y - mn.y) * rsqrtf(vr.y + BNEPS) * gg.y + be.y;
    val.z = (acc.z + bi.z - mn.z) * rsqrtf(vr.z + BNEPS) * gg.z + be.z;
    val.w = (acc.w + bi.w - mn.w) * rsqrtf(vr.w + BNEPS) * gg.w + be.w;
    val.x = val.x > 0.f ? val.x : 0.f;
    val.y = val.y > 0.f ? val.y : 0.f;
    val.z = val.z > 0.f ? val.z : 0.f;
    val.w = val.w > 0.f ? val.w : 0.f;
    union { __hip_bfloat16 b[4]; ushort4 u; } cv;
    cv.b[0] = __float2bfloat16(val.x); cv.b[1] = __float2bfloat16(val.y);
    cv.b[2] = __float2bfloat16(val.z); cv.b[3] = __float2bfloat16(val.w);
    ((ushort4*)hb)[(size_t)node * 64 + lane] = cv.u;
}

// ---------- parallel pooling from bf16 activations ----------
__global__ void k_pool2(const __hip_bfloat16* __restrict__ hb, const int* __restrict__ batch,
                        float* __restrict__ partial) {
    int g = blockIdx.x, i = blockIdx.y, col = threadIdx.x;
    int lo = lower_bound_i(batch, NN, g);
    int hi = lower_bound_i(batch, NN, g + 1);
    int len = hi - lo;
    int a = lo + (int)((long)len * i / PSPLIT);
    int b = lo + (int)((long)len * (i + 1) / PSPLIT);
    float acc = 0.f;
    const unsigned short* hu = (const unsigned short*)hb;
    for (int n = a; n < b; ++n) acc += bf2f(hu[(size_t)n * HIDD + col]);
    partial[((size_t)g * PSPLIT + i) * HIDD + col] = acc;
}

// ---------- final: sum partials + BN + FC ----------
__global__ __launch_bounds__(64) void k_final(const float* __restrict__ partial,
                                              const float* __restrict__ lg,
                                              const float* __restrict__ lb,
                                              const float* __restrict__ lm,
                                              const float* __restrict__ lv,
                                              const float* __restrict__ fcW,
                                              const float* __restrict__ fcb,
                                              float* __restrict__ out) {
    __shared__ float ps[HIDD];
    int g = blockIdx.x, j = threadIdx.x;
    for (int k = j; k < HIDD; k += 64) {
        float s = 0.f;
        for (int i = 0; i < PSPLIT; ++i)
            s += partial[((size_t)g * PSPLIT + i) * HIDD + k];
        ps[k] = (s - lm[k]) * rsqrtf(lv[k] + BNEPS) * lg[k] + lb[k];
    }
    __syncthreads();
    float acc = 0.f;
    for (int k = 0; k < HIDD; ++k)
        acc = fmaf(ps[k], fcW[k * LATD + j], acc);
    out[g * LATD + j] = acc + fcb[j];
}

extern "C" void kernel_launch(void* const* d_in, const int* in_sizes, int n_in,
                              void* d_out, int out_size, void* d_ws, size_t ws_size,
                              hipStream_t stream) {
    const float* x     = (const float*)d_in[0];
    const int*   ei    = (const int*)d_in[1];
    const int*   batch = (const int*)d_in[2];
    const float* W0    = (const float*)d_in[3];
    const float* Wr    = (const float*)d_in[4];
    const float* asrc  = (const float*)d_in[5];
    const float* adst  = (const float*)d_in[6];
    const float* bconv = (const float*)d_in[7];
    const float* bng   = (const float*)d_in[8];
    const float* bnb   = (const float*)d_in[9];
    const float* bnm   = (const float*)d_in[10];
    const float* bnv   = (const float*)d_in[11];
    const float* lg    = (const float*)d_in[12];
    const float* lb    = (const float*)d_in[13];
    const float* lm    = (const float*)d_in[14];
    const float* lv    = (const float*)d_in[15];
    const float* fcW   = (const float*)d_in[16];
    const float* fcb   = (const float*)d_in[17];
    float* out = (float*)d_out;

    char* w = (char*)d_ws;
    size_t off = 0;
    auto alloc = [&](size_t bytes) {
        char* p = w + off;
        off += (bytes + 255) / 256 * 256;
        return p;
    };
    float* al_s  = (float*)alloc((size_t)MPAD * NH * 4);
    float* al_d  = (float*)alloc((size_t)MPAD * NH * 4);
    float* partial = (float*)alloc((size_t)NG * PSPLIT * HIDD * 4);
    __hip_bfloat16* hbx = (__hip_bfloat16*)alloc((size_t)MPAD * IND * 2);   // bf16 x
    __hip_bfloat16* hb2 = (__hip_bfloat16*)alloc((size_t)MPAD * HIDD * 2);  // bf16 activations
    __hip_bfloat16* xpb = (__hip_bfloat16*)alloc((size_t)MPAD * HIDD * 2);  // bf16 xp
    __hip_bfloat16* Wt3 = (__hip_bfloat16*)alloc(((size_t)HIDD * IND + 2 * (size_t)HIDD * HIDD) * 2);
    int* deg     = (int*)alloc((size_t)NN * 4);
    int* row_ptr = (int*)alloc((size_t)(NN + 1) * 4);
    int* cursor  = (int*)alloc((size_t)NN * 4);
    int* col_idx = (int*)alloc((size_t)EE * 4);
    int* bsum    = (int*)alloc((size_t)NB * 4);
    int* boff    = (int*)alloc((size_t)NB * 4);

    // ---- CSR build (dst-sorted edges) ----
    hipLaunchKernelGGL(k_zero, dim3(NB), dim3(256), 0, stream, deg, NN);
    hipLaunchKernelGGL(k_hist, dim3((EE + 255) / 256), dim3(256), 0, stream, ei, deg);
    hipLaunchKernelGGL(k_blocksum, dim3(NB), dim3(256), 0, stream, deg, bsum);
    hipLaunchKernelGGL(k_scanbs, dim3(1), dim3(128), 0, stream, bsum, boff, row_ptr);
    hipLaunchKernelGGL(k_scanapply, dim3(NB), dim3(256), 0, stream, deg, boff, row_ptr, cursor);
    hipLaunchKernelGGL(k_csr_scatter, dim3((EE + 255) / 256), dim3(256), 0, stream,
                       ei, cursor, col_idx);

    hipLaunchKernelGGL(k_cast_x, dim3((NN * IND / 4 + 255) / 256), dim3(256), 0, stream, x, hbx);
    hipLaunchKernelGGL(k_cast_wt_all, dim3(HIDD, 3), dim3(HIDD), 0, stream, W0, Wr, Wt3);

    const size_t wtoff[3] = {0, (size_t)HIDD * IND, (size_t)HIDD * IND + (size_t)HIDD * HIDD};

    for (int layer = 0; layer < 3; ++layer) {
        int K = (layer == 0) ? IND : HIDD;
        const __hip_bfloat16* Ab = (layer == 0) ? hbx : hb2;

        hipLaunchKernelGGL(k_gemm, dim3(MPAD / BM, HIDD / BN), dim3(256), 0, stream,
                           (const short*)Ab, (const short*)(Wt3 + wtoff[layer]), K, xpb,
                           asrc + layer * NH * NC, adst + layer * NH * NC, al_s, al_d);
        hipLaunchKernelGGL(k_gat_agg, dim3((NN + 3) / 4), dim3(256), 0, stream,
                           row_ptr, col_idx, al_s, al_d, xpb,
                           bconv + layer * HIDD, bng + layer * HIDD, bnb + layer * HIDD,
                           bnm + layer * HIDD, bnv + layer * HIDD, hb2);
    }

    hipLaunchKernelGGL(k_pool2, dim3(NG, PSPLIT), dim3(HIDD), 0, stream, hb2, batch, partial);
    hipLaunchKernelGGL(k_final, dim3(NG), dim3(LATD), 0, stream,
                       partial, lg, lb, lm, lv, fcW, fcb, out);
}